// Round 5
// baseline (654.091 us; speedup 1.0000x reference)
//
#include <hip/hip_runtime.h>
#include <stdint.h>

#define NN 10000
#define EE 320000
#define HH1 256
#define HH2 128
#define NSPLIT 4
#define KCH 2560   // K chunk per split (last split: 2320 = 36*64 + 16 tail)

typedef __attribute__((ext_vector_type(8))) short short8;
typedef __attribute__((ext_vector_type(4))) float f32x4;

// RNE f32->bf16 via native cast (compiler packs to v_cvt_pk_bf16_f32).
static __device__ __forceinline__ short f2bf(float f) {
  union { __bf16 h; short s; } u;
  u.h = (__bf16)f;
  return u.s;
}

// ---------------- graph prep ----------------
__global__ void k_count(const int* __restrict__ dst, int* __restrict__ degi) {
  int e = blockIdx.x * 256 + threadIdx.x;
  if (e < EE) atomicAdd(&degi[dst[e]], 1);
}

__global__ __launch_bounds__(1024) void k_scan(const int* __restrict__ degi,
    int* __restrict__ rowst, int* __restrict__ cursor, float* __restrict__ invd) {
  __shared__ int part[1024];
  const int t = threadIdx.x;
  const int chunk = (NN + 1023) / 1024;
  int b = t * chunk, e = b + chunk;
  if (e > NN) e = NN;
  int s = 0;
  for (int i = b; i < e; ++i) s += degi[i];
  part[t] = s;
  __syncthreads();
  for (int off = 1; off < 1024; off <<= 1) {
    int v = (t >= off) ? part[t - off] : 0;
    __syncthreads();
    part[t] += v;
    __syncthreads();
  }
  int base = (t == 0) ? 0 : part[t - 1];
  for (int i = b; i < e; ++i) {
    rowst[i] = base;
    cursor[i] = base;
    invd[i] = 1.0f / (float)(degi[i] + 1);
    base += degi[i];
  }
  if (t == 1023) rowst[NN] = part[1023];
}

__global__ void k_fill(const int* __restrict__ src, const int* __restrict__ dst,
    const float* __restrict__ ew, int* __restrict__ cursor,
    int* __restrict__ csrc, float* __restrict__ cw) {
  int e = blockIdx.x * 256 + threadIdx.x;
  if (e < EE) {
    int p = atomicAdd(&cursor[dst[e]], 1);
    csrc[p] = src[e];
    cw[p] = ew[e];
  }
}

// ---------------- W1 -> bf16 ----------------
__global__ void k_w1bf(const float* __restrict__ W1, short* __restrict__ w1b) {
  long i = (long)(blockIdx.x * 256 + threadIdx.x) * 8;
  float4 a = *(const float4*)(W1 + i);
  float4 b = *(const float4*)(W1 + i + 4);
  short8 o;
  o[0] = f2bf(a.x); o[1] = f2bf(a.y); o[2] = f2bf(a.z); o[3] = f2bf(a.w);
  o[4] = f2bf(b.x); o[5] = f2bf(b.y); o[6] = f2bf(b.z); o[7] = f2bf(b.w);
  *(short8*)(w1b + i) = o;
}

// ---------------- GEMM1: ht1 = feat @ W1^T ----------------
// m97-style async pipeline: ALL staging via global_load_lds (A as f32,
// cvt at LDS-read; B as bf16). Triple-buffered LDS (depth-2 prefetch),
// raw s_barrier + hand-counted s_waitcnt vmcnt(6): chunk i's 6 DMA loads
// drain two intervals after issue; chunk i+1's stay in flight across the
// barrier (no __syncthreads vmcnt(0) drain). K-split 4 into f32 partials.
// LDS swizzle via pre-permuted SOURCE address (linear DMA dest, m173).
__global__ __launch_bounds__(256) void k_gemm1(const float* __restrict__ feat,
    const short* __restrict__ w1b, float* __restrict__ P0, float* __restrict__ P1,
    float* __restrict__ P2, float* __restrict__ P3) {
  __shared__ __align__(16) char gsm[73728];    // 3*(16KB A + 8KB B)
  char* AsB = gsm;              // 3 x 16384: A tiles, f32 [64][64]
  char* BsB = gsm + 49152;      // 3 x  8192: B tiles, bf16 [64][64]
  const int bid = (int)blockIdx.x;
  const int sp = bid / 640;
  const int rr = bid - sp * 640;
  const int g = rr & 7;
  const int c = rr >> 3;
  const int bn = c & 3;
  const int bm = g + ((c >> 2) << 3);
  if (bm * 64 >= NN) return;
  const int ks = sp * KCH;
  const int ke = (ks + KCH < NN) ? ks + KCH : NN;
  float* __restrict__ outp = (sp == 0) ? P0 : (sp == 1) ? P1 : (sp == 2) ? P2 : P3;

  const int t = threadIdx.x;
  const int lane = t & 63;
  const int wid = t >> 6;
  const int wm = wid >> 1, wn = wid & 1;
  const int l15 = lane & 15, l4 = lane >> 4;
  const int aswz = (t & 15) ^ (t >> 4);          // A source 16B-group permutation
  const int bswz = (t & 7) ^ ((t >> 3) & 7);     // B source 16B-group permutation

  f32x4 acc[2][2];
  const f32x4 zz = {0.f, 0.f, 0.f, 0.f};
  acc[0][0] = zz; acc[0][1] = zz; acc[1][0] = zz; acc[1][1] = zz;

#define ISSUE(ci, bufi) do {                                                    \
    const int _k0 = ks + (ci) * 64;                                             \
    _Pragma("unroll")                                                           \
    for (int _j = 0; _j < 4; ++_j) {                                            \
      const int _row = _j * 16 + (t >> 4);                                      \
      const float* _gp = feat + (long)min(bm * 64 + _row, NN - 1) * NN + _k0 + aswz * 4; \
      __builtin_amdgcn_global_load_lds(                                         \
          (const __attribute__((address_space(1))) unsigned int*)_gp,           \
          (__attribute__((address_space(3))) unsigned int*)(AsB + (bufi) * 16384 + _j * 4096 + t * 16), \
          16, 0, 0);                                                            \
    }                                                                           \
    _Pragma("unroll")                                                           \
    for (int _j = 0; _j < 2; ++_j) {                                            \
      const int _row = _j * 32 + (t >> 3);                                      \
      const short* _gp = w1b + (long)(bn * 64 + _row) * NN + _k0 + bswz * 8;    \
      __builtin_amdgcn_global_load_lds(                                         \
          (const __attribute__((address_space(1))) unsigned int*)_gp,           \
          (__attribute__((address_space(3))) unsigned int*)(BsB + (bufi) * 8192 + _j * 4096 + t * 16), \
          16, 0, 0);                                                            \
    }                                                                           \
  } while (0)

  const int nch = (ke - ks) >> 6;   // 40, 40, 40, 36
  ISSUE(0, 0);
  ISSUE(1, 1);
  int cur = 0;
  for (int ci = 0; ci < nch; ++ci) {
    if (ci + 1 < nch) {
      asm volatile("s_waitcnt vmcnt(6)" ::: "memory");   // chunk ci landed; ci+1 in flight
    } else {
      asm volatile("s_waitcnt vmcnt(0)" ::: "memory");
    }
    __builtin_amdgcn_s_barrier();                        // raw: no vmcnt(0) drain
    asm volatile("" ::: "memory");
    if (ci + 2 < nch) {
      int bnext = cur + 2; if (bnext >= 3) bnext -= 3;
      ISSUE(ci + 2, bnext);
    }
    const char* abase = AsB + cur * 16384;
    const char* bbase = BsB + cur * 8192;
#pragma unroll
    for (int kk = 0; kk < 2; ++kk) {
      const int Ra0 = wm * 32 + l15;
      const int Ra1 = Ra0 + 16;
      const int Rb0 = wn * 32 + l15;
      const int Rb1 = Rb0 + 16;
      const int g0 = kk * 8 + l4 * 2;
      float4 lo0 = *(const float4*)(abase + Ra0 * 256 + ((g0 ^ (Ra0 & 15)) * 16));
      float4 hi0 = *(const float4*)(abase + Ra0 * 256 + (((g0 + 1) ^ (Ra0 & 15)) * 16));
      float4 lo1 = *(const float4*)(abase + Ra1 * 256 + ((g0 ^ (Ra1 & 15)) * 16));
      float4 hi1 = *(const float4*)(abase + Ra1 * 256 + (((g0 + 1) ^ (Ra1 & 15)) * 16));
      short8 af0, af1;
      af0[0] = f2bf(lo0.x); af0[1] = f2bf(lo0.y); af0[2] = f2bf(lo0.z); af0[3] = f2bf(lo0.w);
      af0[4] = f2bf(hi0.x); af0[5] = f2bf(hi0.y); af0[6] = f2bf(hi0.z); af0[7] = f2bf(hi0.w);
      af1[0] = f2bf(lo1.x); af1[1] = f2bf(lo1.y); af1[2] = f2bf(lo1.z); af1[3] = f2bf(lo1.w);
      af1[4] = f2bf(hi1.x); af1[5] = f2bf(hi1.y); af1[6] = f2bf(hi1.z); af1[7] = f2bf(hi1.w);
      const int gb = kk * 4 + l4;
      short8 bf0 = *(const short8*)(bbase + Rb0 * 128 + ((gb ^ (Rb0 & 7)) * 16));
      short8 bf1 = *(const short8*)(bbase + Rb1 * 128 + ((gb ^ (Rb1 & 7)) * 16));
      acc[0][0] = __builtin_amdgcn_mfma_f32_16x16x32_bf16(af0, bf0, acc[0][0], 0, 0, 0);
      acc[0][1] = __builtin_amdgcn_mfma_f32_16x16x32_bf16(af0, bf1, acc[0][1], 0, 0, 0);
      acc[1][0] = __builtin_amdgcn_mfma_f32_16x16x32_bf16(af1, bf0, acc[1][0], 0, 0, 0);
      acc[1][1] = __builtin_amdgcn_mfma_f32_16x16x32_bf16(af1, bf1, acc[1][1], 0, 0, 0);
    }
    cur = (cur + 1 == 3) ? 0 : cur + 1;
  }
#undef ISSUE

  // K tail (sp==3 only): 16 columns, reg-direct MFMA; k>=16 lanes contribute 0.
  if (ks + (nch << 6) < ke) {
    const int kt = ks + (nch << 6);              // 9984; row reads end exactly at NN
    const short8 z8 = {0, 0, 0, 0, 0, 0, 0, 0};
    short8 aft0 = z8, aft1 = z8, bft0 = z8, bft1 = z8;
    if (l4 < 2) {
      const long Ra0 = (long)min(bm * 64 + wm * 32 + l15, NN - 1) * NN + kt + l4 * 8;
      const long Ra1 = (long)min(bm * 64 + wm * 32 + 16 + l15, NN - 1) * NN + kt + l4 * 8;
      float4 lo0 = *(const float4*)(feat + Ra0);
      float4 hi0 = *(const float4*)(feat + Ra0 + 4);
      float4 lo1 = *(const float4*)(feat + Ra1);
      float4 hi1 = *(const float4*)(feat + Ra1 + 4);
      aft0[0] = f2bf(lo0.x); aft0[1] = f2bf(lo0.y); aft0[2] = f2bf(lo0.z); aft0[3] = f2bf(lo0.w);
      aft0[4] = f2bf(hi0.x); aft0[5] = f2bf(hi0.y); aft0[6] = f2bf(hi0.z); aft0[7] = f2bf(hi0.w);
      aft1[0] = f2bf(lo1.x); aft1[1] = f2bf(lo1.y); aft1[2] = f2bf(lo1.z); aft1[3] = f2bf(lo1.w);
      aft1[4] = f2bf(hi1.x); aft1[5] = f2bf(hi1.y); aft1[6] = f2bf(hi1.z); aft1[7] = f2bf(hi1.w);
      bft0 = *(const short8*)(w1b + (long)(bn * 64 + wn * 32 + l15) * NN + kt + l4 * 8);
      bft1 = *(const short8*)(w1b + (long)(bn * 64 + wn * 32 + 16 + l15) * NN + kt + l4 * 8);
    }
    acc[0][0] = __builtin_amdgcn_mfma_f32_16x16x32_bf16(aft0, bft0, acc[0][0], 0, 0, 0);
    acc[0][1] = __builtin_amdgcn_mfma_f32_16x16x32_bf16(aft0, bft1, acc[0][1], 0, 0, 0);
    acc[1][0] = __builtin_amdgcn_mfma_f32_16x16x32_bf16(aft1, bft0, acc[1][0], 0, 0, 0);
    acc[1][1] = __builtin_amdgcn_mfma_f32_16x16x32_bf16(aft1, bft1, acc[1][1], 0, 0, 0);
  }

#pragma unroll
  for (int mi = 0; mi < 2; ++mi) {
    const int row0 = bm * 64 + wm * 32 + mi * 16 + l4 * 4;
#pragma unroll
    for (int ni = 0; ni < 2; ++ni) {
      const int cc = bn * 64 + wn * 32 + ni * 16 + l15;
#pragma unroll
      for (int r2 = 0; r2 < 4; ++r2) {
        const int row = row0 + r2;
        if (row < NN) outp[(long)row * HH1 + cc] = acc[mi][ni][r2];
      }
    }
  }
}

// ---------------- reduce 4 partials -> ht1 --------------
__global__ void k_red1(const float* __restrict__ P0, const float* __restrict__ P1,
    const float* __restrict__ P2, const float* __restrict__ P3,
    float* __restrict__ o) {
  const long i = (long)(blockIdx.x * 256 + threadIdx.x) * 4;
  f32x4 a = *(const f32x4*)(P0 + i);
  f32x4 b = *(const f32x4*)(P1 + i);
  f32x4 c = *(const f32x4*)(P2 + i);
  f32x4 d = *(const f32x4*)(P3 + i);
  *(f32x4*)(o + i) = (a + b) + (c + d);
}

// ---------------- aggregate layer 1 (+relu) ----------------
__global__ void k_agg1(const float* __restrict__ ht1, const int* __restrict__ rowst,
    const int* __restrict__ csrc, const float* __restrict__ cw,
    const float* __restrict__ invd, const float* __restrict__ b1,
    float* __restrict__ h) {
  const int node = blockIdx.x;
  const int j = threadIdx.x;
  const int s = rowst[node], e = rowst[node + 1];
  float acc = 0.f;
  for (int p = s; p < e; ++p)
    acc = fmaf(cw[p], ht1[(long)csrc[p] * HH1 + j], acc);
  float v = (acc + ht1[(long)node * HH1 + j]) * invd[node] + b1[j];
  h[(long)node * HH1 + j] = fmaxf(v, 0.f);
}

// ---------------- GEMM2: ht2 = h @ W2^T (f32 VALU) ----------------
__global__ __launch_bounds__(512) void k_gemm2(const float* __restrict__ h,
    const float* __restrict__ W2, float* __restrict__ ht2) {
  const int t = threadIdx.x;
  const int col = t & 127, rg = t >> 7;  // rg 0..3
  const long row0 = (long)blockIdx.x * 16 + rg * 4;
  const float* hp = h + row0 * HH1;
  const float* wp = W2 + col * HH1;
  float acc0 = 0.f, acc1 = 0.f, acc2 = 0.f, acc3 = 0.f;
  for (int k = 0; k < HH1; k += 4) {
    float4 wv = *(const float4*)(wp + k);
    float4 h0 = *(const float4*)(hp + k);
    float4 h1 = *(const float4*)(hp + HH1 + k);
    float4 h2 = *(const float4*)(hp + 2 * HH1 + k);
    float4 h3 = *(const float4*)(hp + 3 * HH1 + k);
    acc0 += h0.x * wv.x + h0.y * wv.y + h0.z * wv.z + h0.w * wv.w;
    acc1 += h1.x * wv.x + h1.y * wv.y + h1.z * wv.z + h1.w * wv.w;
    acc2 += h2.x * wv.x + h2.y * wv.y + h2.z * wv.z + h2.w * wv.w;
    acc3 += h3.x * wv.x + h3.y * wv.y + h3.z * wv.z + h3.w * wv.w;
  }
  ht2[row0 * HH2 + col] = acc0;
  ht2[(row0 + 1) * HH2 + col] = acc1;
  ht2[(row0 + 2) * HH2 + col] = acc2;
  ht2[(row0 + 3) * HH2 + col] = acc3;
}

// ---------------- aggregate layer 2 -> z (f32 out) + pre-swizzled bf16 ------
__global__ void k_agg2(const float* __restrict__ ht2, const int* __restrict__ rowst,
    const int* __restrict__ csrc, const float* __restrict__ cw,
    const float* __restrict__ invd, const float* __restrict__ b2,
    float* __restrict__ zout, short* __restrict__ zb) {
  const int node = blockIdx.x;
  const int j = threadIdx.x;
  const int s = rowst[node], e = rowst[node + 1];
  float acc = 0.f;
  for (int p = s; p < e; ++p)
    acc = fmaf(cw[p], ht2[(long)csrc[p] * HH2 + j], acc);
  float v = (acc + ht2[(long)node * HH2 + j]) * invd[node] + b2[j];
  zout[(long)node * HH2 + j] = v;
  const int slot = j >> 3, pos = j & 7;
  zb[node * HH2 + ((slot ^ (node & 15)) << 3) + pos] = f2bf(v);
}

// ---------------- adj = z @ z^T (bf16 MFMA, K=128, tile 128x128) ------------
// Epilogue: LDS-transpose accumulators (reusing staging LDS, XOR-swizzled)
// so global stores are dwordx4 with 512B contiguous per output row.
static __device__ __forceinline__ int xsw(int row) {
  return (((row >> 2) & 1) << 4) ^ (((row >> 3) & 3) << 2);
}

__global__ __launch_bounds__(256) void k_adj(const short* __restrict__ zb,
                                             float* __restrict__ adj) {
  __shared__ __align__(16) char smem[65536];
  short* As = (short*)smem;            // 32KB bf16 [128][128]
  short* Bs = (short*)(smem + 32768);  // 32KB
  const int bmi = blockIdx.y, bni = blockIdx.x;
  const int t = threadIdx.x;
  const int lane = t & 63;
  const int wid = t >> 6;
  const int wm = wid >> 1, wn = wid & 1;
  const int l15 = lane & 15, l4 = lane >> 4;
  const int sr = t >> 4;   // 0..15
  const int ss = t & 15;
#pragma unroll
  for (int it = 0; it < 8; ++it) {
    const int r = it * 16 + sr;
    const long ga = (long)min(bmi * 128 + r, NN - 1) * HH2;
    const long gb = (long)min(bni * 128 + r, NN - 1) * HH2;
    *(short8*)(As + r * 128 + ss * 8) = *(const short8*)(zb + ga + ss * 8);
    *(short8*)(Bs + r * 128 + ss * 8) = *(const short8*)(zb + gb + ss * 8);
  }
  __syncthreads();
  f32x4 acc[4][4];
  const f32x4 zz = {0.f, 0.f, 0.f, 0.f};
#pragma unroll
  for (int mi = 0; mi < 4; ++mi)
#pragma unroll
    for (int ni = 0; ni < 4; ++ni) acc[mi][ni] = zz;
#pragma unroll
  for (int k4 = 0; k4 < 4; ++k4) {
    const int es = ((k4 * 4 + l4) ^ l15) * 8;
    short8 af[4], bf[4];
#pragma unroll
    for (int mi = 0; mi < 4; ++mi)
      af[mi] = *(const short8*)(As + (wm * 64 + mi * 16 + l15) * 128 + es);
#pragma unroll
    for (int ni = 0; ni < 4; ++ni)
      bf[ni] = *(const short8*)(Bs + (wn * 64 + ni * 16 + l15) * 128 + es);
#pragma unroll
    for (int mi = 0; mi < 4; ++mi)
#pragma unroll
      for (int ni = 0; ni < 4; ++ni)
        acc[mi][ni] = __builtin_amdgcn_mfma_f32_16x16x32_bf16(af[mi], bf[ni], acc[mi][ni], 0, 0, 0);
  }
  __syncthreads();                       // staging reads done; reuse LDS
  float* Cs = (float*)smem;              // 64KB f32 [128][128], swizzled cols
#pragma unroll
  for (int mi = 0; mi < 4; ++mi) {
#pragma unroll
    for (int ni = 0; ni < 4; ++ni) {
      const int col = wn * 64 + ni * 16 + l15;
#pragma unroll
      for (int r = 0; r < 4; ++r) {
        const int row = wm * 64 + mi * 16 + l4 * 4 + r;
        Cs[row * 128 + (col ^ xsw(row))] = acc[mi][ni][r];
      }
    }
  }
  __syncthreads();
  const int rof = t >> 5;                // 0..7
  const int c0 = (t & 31) * 4;           // 0..124
#pragma unroll
  for (int i = 0; i < 16; ++i) {
    const int row = i * 8 + rof;
    const int grow = bmi * 128 + row;
    if (grow < NN) {
      f32x4 v = *(const f32x4*)(&Cs[row * 128 + (c0 ^ xsw(row))]);
      const int gcol = bni * 128 + c0;
      if (gcol + 3 < NN) {
        *(f32x4*)(adj + (long)grow * NN + gcol) = v;
      } else {
#pragma unroll
        for (int e2 = 0; e2 < 4; ++e2)
          if (gcol + e2 < NN) adj[(long)grow * NN + gcol + e2] = v[e2];
      }
    }
  }
}

// ---------------- launch ----------------
extern "C" void kernel_launch(void* const* d_in, const int* in_sizes, int n_in,
                              void* d_out, int out_size, void* d_ws, size_t ws_size,
                              hipStream_t stream) {
  (void)in_sizes; (void)n_in; (void)out_size; (void)ws_size;
  const float* feat = (const float*)d_in[0];
  const float* W1   = (const float*)d_in[1];
  const float* b1   = (const float*)d_in[2];
  const float* W2   = (const float*)d_in[3];
  const float* b2   = (const float*)d_in[4];
  const float* ew   = (const float*)d_in[5];
  const int*   srcv = (const int*)d_in[6];
  const int*   dstv = (const int*)d_in[7];

  float* zout = (float*)d_out;
  float* adj  = zout + (long)NN * HH2;

  // workspace layout
  float* ht1  = (float*)d_ws;                 // NN*HH1 f32 = partial 0; later ht2
  float* hbuf = ht1 + (long)NN * HH1;         // NN*HH1 f32 = partial 1; later h
  short* w1b  = (short*)(hbuf + (long)NN * HH1); // NN*HH1 bf16
  short* zb   = w1b + (long)NN * HH1;         // NN*HH2 bf16 (pre-swizzled)
  int*   degi = (int*)(zb + (long)NN * HH2);  // NN
  int*   rowst = degi + NN;                   // NN+1 (pad 16)
  int*   cursor = rowst + NN + 16;            // NN
  int*   csrc = cursor + NN;                  // EE
  float* cw   = (float*)(csrc + EE);          // EE
  float* invd = cw + EE;                      // NN
  float* P2   = invd + NN + 16;               // NN*HH1 f32 = partial 2
  float* P3   = P2 + (long)NN * HH1;          // NN*HH1 f32 = partial 3
  float* ht2  = ht1;                          // alias (ht1 dead after k_agg1)

  hipMemsetAsync(degi, 0, NN * sizeof(int), stream);
  k_count<<<(EE + 255) / 256, 256, 0, stream>>>(dstv, degi);
  k_scan<<<1, 1024, 0, stream>>>(degi, rowst, cursor, invd);
  k_fill<<<(EE + 255) / 256, 256, 0, stream>>>(srcv, dstv, ew, cursor, csrc, cw);
  k_w1bf<<<1250, 256, 0, stream>>>(W1, w1b);
  k_gemm1<<<640 * NSPLIT, 256, 0, stream>>>(feat, w1b, ht1, hbuf, P2, P3);
  k_red1<<<2500, 256, 0, stream>>>(ht1, hbuf, P2, P3, ht1);
  k_agg1<<<NN, 256, 0, stream>>>(ht1, rowst, csrc, cw, invd, b1, hbuf);
  k_gemm2<<<625, 512, 0, stream>>>(hbuf, W2, ht2);
  k_agg2<<<NN, 128, 0, stream>>>(ht2, rowst, csrc, cw, invd, b2, zout, zb);
  k_adj<<<dim3(79, 79), 256, 0, stream>>>(zb, adj);
}

// Round 7
// 561.763 us; speedup vs baseline: 1.1644x; 1.1644x over previous
//
#include <hip/hip_runtime.h>
#include <stdint.h>

#define NN 10000
#define EE 320000
#define HH1 256
#define HH2 128
#define NSPLIT 4
#define KCH 2560   // K chunk per split (last split: 2320 = 36*64 + 16 tail)

typedef __attribute__((ext_vector_type(8))) short short8;
typedef __attribute__((ext_vector_type(4))) float f32x4;

// RNE f32->bf16 via native cast (compiler packs to v_cvt_pk_bf16_f32).
static __device__ __forceinline__ short f2bf(float f) {
  union { __bf16 h; short s; } u;
  u.h = (__bf16)f;
  return u.s;
}

static __device__ __forceinline__ short8 cvt8(f32x4 a, f32x4 b) {
  short8 o;
  o[0] = f2bf(a[0]); o[1] = f2bf(a[1]); o[2] = f2bf(a[2]); o[3] = f2bf(a[3]);
  o[4] = f2bf(b[0]); o[5] = f2bf(b[1]); o[6] = f2bf(b[2]); o[7] = f2bf(b[3]);
  return o;
}

// ---------------- graph prep ----------------
__global__ void k_count(const int* __restrict__ dst, int* __restrict__ degi) {
  int e = blockIdx.x * 256 + threadIdx.x;
  if (e < EE) atomicAdd(&degi[dst[e]], 1);
}

__global__ __launch_bounds__(1024) void k_scan(const int* __restrict__ degi,
    int* __restrict__ rowst, int* __restrict__ cursor, float* __restrict__ invd) {
  __shared__ int part[1024];
  const int t = threadIdx.x;
  const int chunk = (NN + 1023) / 1024;
  int b = t * chunk, e = b + chunk;
  if (e > NN) e = NN;
  int s = 0;
  for (int i = b; i < e; ++i) s += degi[i];
  part[t] = s;
  __syncthreads();
  for (int off = 1; off < 1024; off <<= 1) {
    int v = (t >= off) ? part[t - off] : 0;
    __syncthreads();
    part[t] += v;
    __syncthreads();
  }
  int base = (t == 0) ? 0 : part[t - 1];
  for (int i = b; i < e; ++i) {
    rowst[i] = base;
    cursor[i] = base;
    invd[i] = 1.0f / (float)(degi[i] + 1);
    base += degi[i];
  }
  if (t == 1023) rowst[NN] = part[1023];
}

__global__ void k_fill(const int* __restrict__ src, const int* __restrict__ dst,
    const float* __restrict__ ew, int* __restrict__ cursor,
    int* __restrict__ csrc, float* __restrict__ cw) {
  int e = blockIdx.x * 256 + threadIdx.x;
  if (e < EE) {
    int p = atomicAdd(&cursor[dst[e]], 1);
    csrc[p] = src[e];
    cw[p] = ew[e];
  }
}

// ---------------- W1 -> bf16 ----------------
__global__ void k_w1bf(const float* __restrict__ W1, short* __restrict__ w1b) {
  long i = (long)(blockIdx.x * 256 + threadIdx.x) * 8;
  float4 a = *(const float4*)(W1 + i);
  float4 b = *(const float4*)(W1 + i + 4);
  short8 o;
  o[0] = f2bf(a.x); o[1] = f2bf(a.y); o[2] = f2bf(a.z); o[3] = f2bf(a.w);
  o[4] = f2bf(b.x); o[5] = f2bf(b.y); o[6] = f2bf(b.z); o[7] = f2bf(b.w);
  *(short8*)(w1b + i) = o;
}

// ---------------- GEMM1: ht1 = feat @ W1^T ----------------
// BM=64, BN=256 (full width: feat read ONCE, no bn re-read), BK=64.
// K-split 4 into f32 partials (k_red1 sums). 4 waves, wave-tile 32x128,
// 32 MFMAs/wave/chunk. LDS 40KB (A 8KB single + B 32KB).
// Prefetch via inline-asm global_load_dwordx4 (compiler can't sink it),
// consumed next chunk after explicit vmcnt(0); raw s_barrier (no vmcnt
// drain) keeps the 12 loads in flight across the MFMA body.
// dwordx4 = 16 BYTES: A row slice q*16..q*16+15 f32 = byte offsets 0/16/32/48.
__global__ __launch_bounds__(256, 3) void k_gemm1(const float* __restrict__ feat,
    const short* __restrict__ w1b, float* __restrict__ P0, float* __restrict__ P1,
    float* __restrict__ P2, float* __restrict__ P3) {
  __shared__ short Abuf[64 * 64];    // bf16 [64 rows][64 k], slot^(row&7) swizzle
  __shared__ short Bbuf[256 * 64];   // bf16 [256 rows][64 k], same swizzle
  const int bid = (int)blockIdx.x;
  const int sp = bid / 157;
  const int bm = bid - sp * 157;
  const int ks = sp * KCH;
  const int ke = (ks + KCH < NN) ? ks + KCH : NN;
  float* __restrict__ outp = (sp == 0) ? P0 : (sp == 1) ? P1 : (sp == 2) ? P2 : P3;

  const int t = threadIdx.x;
  const int lane = t & 63;
  const int wid = t >> 6;
  const int wm = wid >> 1, wn = wid & 1;          // wave grid 2m x 2n
  const int l15 = lane & 15, l4 = lane >> 4;
  const int ar = t >> 2, q = t & 3;               // A staging: row, col-quarter
  const long abase = (long)min(bm * 64 + ar, NN - 1) * NN + q * 16;
  const long bbase = (long)t * NN;                // B staging: row t (=out col)

  f32x4 acc0[8], acc1[8];
  const f32x4 zz = {0.f, 0.f, 0.f, 0.f};
#pragma unroll
  for (int ni = 0; ni < 8; ++ni) { acc0[ni] = zz; acc1[ni] = zz; }

  f32x4 ra0, ra1, ra2, ra3;
  short8 rb0, rb1, rb2, rb3, rb4, rb5, rb6, rb7;

#define GLOAD_A(PTR)                                                           \
  asm volatile("global_load_dwordx4 %0, %4, off\n\t"                           \
               "global_load_dwordx4 %1, %4, off offset:16\n\t"                 \
               "global_load_dwordx4 %2, %4, off offset:32\n\t"                 \
               "global_load_dwordx4 %3, %4, off offset:48"                     \
               : "=&v"(ra0), "=&v"(ra1), "=&v"(ra2), "=&v"(ra3)                \
               : "v"(PTR) : "memory")

#define GLOAD_B(PTR)                                                           \
  asm volatile("global_load_dwordx4 %0, %8, off\n\t"                           \
               "global_load_dwordx4 %1, %8, off offset:16\n\t"                 \
               "global_load_dwordx4 %2, %8, off offset:32\n\t"                 \
               "global_load_dwordx4 %3, %8, off offset:48\n\t"                 \
               "global_load_dwordx4 %4, %8, off offset:64\n\t"                 \
               "global_load_dwordx4 %5, %8, off offset:80\n\t"                 \
               "global_load_dwordx4 %6, %8, off offset:96\n\t"                 \
               "global_load_dwordx4 %7, %8, off offset:112"                    \
               : "=&v"(rb0), "=&v"(rb1), "=&v"(rb2), "=&v"(rb3),               \
                 "=&v"(rb4), "=&v"(rb5), "=&v"(rb6), "=&v"(rb7)                \
               : "v"(PTR) : "memory")

  const int nch = (ke - ks) >> 6;   // 40,40,40,36
  GLOAD_A(feat + abase + ks);
  GLOAD_B(w1b + bbase + ks);

  const int asw0 = ((2 * q) ^ (ar & 7)) * 8;
  const int asw1 = ((2 * q + 1) ^ (ar & 7)) * 8;

  for (int ci = 0; ci < nch; ++ci) {
    asm volatile("s_waitcnt vmcnt(0)" ::: "memory");   // prev-issued loads landed
    // stage A (cvt f32->bf16) and B into LDS, swizzled slot^(row&7)
    *(short8*)(Abuf + ar * 64 + asw0) = cvt8(ra0, ra1);
    *(short8*)(Abuf + ar * 64 + asw1) = cvt8(ra2, ra3);
    *(short8*)(Bbuf + t * 64 + ((0 ^ (t & 7)) * 8)) = rb0;
    *(short8*)(Bbuf + t * 64 + ((1 ^ (t & 7)) * 8)) = rb1;
    *(short8*)(Bbuf + t * 64 + ((2 ^ (t & 7)) * 8)) = rb2;
    *(short8*)(Bbuf + t * 64 + ((3 ^ (t & 7)) * 8)) = rb3;
    *(short8*)(Bbuf + t * 64 + ((4 ^ (t & 7)) * 8)) = rb4;
    *(short8*)(Bbuf + t * 64 + ((5 ^ (t & 7)) * 8)) = rb5;
    *(short8*)(Bbuf + t * 64 + ((6 ^ (t & 7)) * 8)) = rb6;
    *(short8*)(Bbuf + t * 64 + ((7 ^ (t & 7)) * 8)) = rb7;
    // issue next chunk's loads (stay in flight across the barriers)
    if (ci + 1 < nch) {
      const int kn = ks + (ci + 1) * 64;
      GLOAD_A(feat + abase + kn);
      GLOAD_B(w1b + bbase + kn);
    }
    asm volatile("s_waitcnt lgkmcnt(0)" ::: "memory"); // my LDS writes done
    asm volatile("s_barrier" ::: "memory");            // all writes visible
    __builtin_amdgcn_sched_barrier(0);
#pragma unroll
    for (int kk = 0; kk < 2; ++kk) {
      const int es = ((kk * 4 + l4) ^ (l15 & 7)) * 8;
      const short8 af0 = *(const short8*)(Abuf + (wm * 32 + l15) * 64 + es);
      const short8 af1 = *(const short8*)(Abuf + (wm * 32 + 16 + l15) * 64 + es);
#pragma unroll
      for (int ni = 0; ni < 8; ++ni) {
        const short8 bf = *(const short8*)(Bbuf + (wn * 128 + ni * 16 + l15) * 64 + es);
        acc0[ni] = __builtin_amdgcn_mfma_f32_16x16x32_bf16(af0, bf, acc0[ni], 0, 0, 0);
        acc1[ni] = __builtin_amdgcn_mfma_f32_16x16x32_bf16(af1, bf, acc1[ni], 0, 0, 0);
      }
    }
    __builtin_amdgcn_sched_barrier(0);
    asm volatile("s_waitcnt lgkmcnt(0)" ::: "memory"); // my ds_reads complete
    asm volatile("s_barrier" ::: "memory");            // reads done before rewrite
  }
#undef GLOAD_A
#undef GLOAD_B

  // K tail (sp==3): 16 columns, reg-direct MFMA; lanes l4>=2 contribute 0.
  if (ks + (nch << 6) < ke) {
    const int kt = ks + (nch << 6);                    // 9984
    const short8 z8 = {0, 0, 0, 0, 0, 0, 0, 0};
    short8 aft0 = z8, aft1 = z8;
    short8 bft[8];
#pragma unroll
    for (int ni = 0; ni < 8; ++ni) bft[ni] = z8;
    if (l4 < 2) {
      const long Ra0 = (long)min(bm * 64 + wm * 32 + l15, NN - 1) * NN + kt + l4 * 8;
      const long Ra1 = (long)min(bm * 64 + wm * 32 + 16 + l15, NN - 1) * NN + kt + l4 * 8;
      f32x4 lo0 = *(const f32x4*)(feat + Ra0);
      f32x4 hi0 = *(const f32x4*)(feat + Ra0 + 4);
      f32x4 lo1 = *(const f32x4*)(feat + Ra1);
      f32x4 hi1 = *(const f32x4*)(feat + Ra1 + 4);
      aft0 = cvt8(lo0, hi0);
      aft1 = cvt8(lo1, hi1);
#pragma unroll
      for (int ni = 0; ni < 8; ++ni)
        bft[ni] = *(const short8*)(w1b + (long)(wn * 128 + ni * 16 + l15) * NN + kt + l4 * 8);
    }
#pragma unroll
    for (int ni = 0; ni < 8; ++ni) {
      acc0[ni] = __builtin_amdgcn_mfma_f32_16x16x32_bf16(aft0, bft[ni], acc0[ni], 0, 0, 0);
      acc1[ni] = __builtin_amdgcn_mfma_f32_16x16x32_bf16(aft1, bft[ni], acc1[ni], 0, 0, 0);
    }
  }

  // epilogue: write 64x256 f32 partial
#pragma unroll
  for (int ni = 0; ni < 8; ++ni) {
    const int col = wn * 128 + ni * 16 + l15;
    const int r0 = bm * 64 + wm * 32 + l4 * 4;
#pragma unroll
    for (int r2 = 0; r2 < 4; ++r2) {
      const int row = r0 + r2;
      if (row < NN) outp[(long)row * HH1 + col] = acc0[ni][r2];
      if (row + 16 < NN) outp[(long)(row + 16) * HH1 + col] = acc1[ni][r2];
    }
  }
}

// ---------------- reduce 4 partials -> ht1 --------------
__global__ void k_red1(const float* __restrict__ P0, const float* __restrict__ P1,
    const float* __restrict__ P2, const float* __restrict__ P3,
    float* __restrict__ o) {
  const long i = (long)(blockIdx.x * 256 + threadIdx.x) * 4;
  f32x4 a = *(const f32x4*)(P0 + i);
  f32x4 b = *(const f32x4*)(P1 + i);
  f32x4 c = *(const f32x4*)(P2 + i);
  f32x4 d = *(const f32x4*)(P3 + i);
  *(f32x4*)(o + i) = (a + b) + (c + d);
}

// ---------------- aggregate layer 1 (+relu) ----------------
__global__ void k_agg1(const float* __restrict__ ht1, const int* __restrict__ rowst,
    const int* __restrict__ csrc, const float* __restrict__ cw,
    const float* __restrict__ invd, const float* __restrict__ b1,
    float* __restrict__ h) {
  const int node = blockIdx.x;
  const int j = threadIdx.x;
  const int s = rowst[node], e = rowst[node + 1];
  float acc = 0.f;
  for (int p = s; p < e; ++p)
    acc = fmaf(cw[p], ht1[(long)csrc[p] * HH1 + j], acc);
  float v = (acc + ht1[(long)node * HH1 + j]) * invd[node] + b1[j];
  h[(long)node * HH1 + j] = fmaxf(v, 0.f);
}

// ---------------- GEMM2: ht2 = h @ W2^T (f32 VALU) ----------------
__global__ __launch_bounds__(512) void k_gemm2(const float* __restrict__ h,
    const float* __restrict__ W2, float* __restrict__ ht2) {
  const int t = threadIdx.x;
  const int col = t & 127, rg = t >> 7;  // rg 0..3
  const long row0 = (long)blockIdx.x * 16 + rg * 4;
  const float* hp = h + row0 * HH1;
  const float* wp = W2 + col * HH1;
  float acc0 = 0.f, acc1 = 0.f, acc2 = 0.f, acc3 = 0.f;
  for (int k = 0; k < HH1; k += 4) {
    float4 wv = *(const float4*)(wp + k);
    float4 h0 = *(const float4*)(hp + k);
    float4 h1 = *(const float4*)(hp + HH1 + k);
    float4 h2 = *(const float4*)(hp + 2 * HH1 + k);
    float4 h3 = *(const float4*)(hp + 3 * HH1 + k);
    acc0 += h0.x * wv.x + h0.y * wv.y + h0.z * wv.z + h0.w * wv.w;
    acc1 += h1.x * wv.x + h1.y * wv.y + h1.z * wv.z + h1.w * wv.w;
    acc2 += h2.x * wv.x + h2.y * wv.y + h2.z * wv.z + h2.w * wv.w;
    acc3 += h3.x * wv.x + h3.y * wv.y + h3.z * wv.z + h3.w * wv.w;
  }
  ht2[row0 * HH2 + col] = acc0;
  ht2[(row0 + 1) * HH2 + col] = acc1;
  ht2[(row0 + 2) * HH2 + col] = acc2;
  ht2[(row0 + 3) * HH2 + col] = acc3;
}

// ---------------- aggregate layer 2 -> z (f32 out) + pre-swizzled bf16 ------
__global__ void k_agg2(const float* __restrict__ ht2, const int* __restrict__ rowst,
    const int* __restrict__ csrc, const float* __restrict__ cw,
    const float* __restrict__ invd, const float* __restrict__ b2,
    float* __restrict__ zout, short* __restrict__ zb) {
  const int node = blockIdx.x;
  const int j = threadIdx.x;
  const int s = rowst[node], e = rowst[node + 1];
  float acc = 0.f;
  for (int p = s; p < e; ++p)
    acc = fmaf(cw[p], ht2[(long)csrc[p] * HH2 + j], acc);
  float v = (acc + ht2[(long)node * HH2 + j]) * invd[node] + b2[j];
  zout[(long)node * HH2 + j] = v;
  const int slot = j >> 3, pos = j & 7;
  zb[node * HH2 + ((slot ^ (node & 15)) << 3) + pos] = f2bf(v);
}

// ---------------- adj = z @ z^T (bf16 MFMA, K=128, tile 128x128) ------------
// Epilogue: LDS-transpose accumulators (reusing staging LDS, XOR-swizzled)
// so global stores are dwordx4 with 512B contiguous per output row.
static __device__ __forceinline__ int xsw(int row) {
  return (((row >> 2) & 1) << 4) ^ (((row >> 3) & 3) << 2);
}

__global__ __launch_bounds__(256) void k_adj(const short* __restrict__ zb,
                                             float* __restrict__ adj) {
  __shared__ __align__(16) char smem[65536];
  short* As = (short*)smem;            // 32KB bf16 [128][128]
  short* Bs = (short*)(smem + 32768);  // 32KB
  const int bmi = blockIdx.y, bni = blockIdx.x;
  const int t = threadIdx.x;
  const int lane = t & 63;
  const int wid = t >> 6;
  const int wm = wid >> 1, wn = wid & 1;
  const int l15 = lane & 15, l4 = lane >> 4;
  const int sr = t >> 4;   // 0..15
  const int ss = t & 15;
#pragma unroll
  for (int it = 0; it < 8; ++it) {
    const int r = it * 16 + sr;
    const long ga = (long)min(bmi * 128 + r, NN - 1) * HH2;
    const long gb = (long)min(bni * 128 + r, NN - 1) * HH2;
    *(short8*)(As + r * 128 + ss * 8) = *(const short8*)(zb + ga + ss * 8);
    *(short8*)(Bs + r * 128 + ss * 8) = *(const short8*)(zb + gb + ss * 8);
  }
  __syncthreads();
  f32x4 acc[4][4];
  const f32x4 zz = {0.f, 0.f, 0.f, 0.f};
#pragma unroll
  for (int mi = 0; mi < 4; ++mi)
#pragma unroll
    for (int ni = 0; ni < 4; ++ni) acc[mi][ni] = zz;
#pragma unroll
  for (int k4 = 0; k4 < 4; ++k4) {
    const int es = ((k4 * 4 + l4) ^ l15) * 8;
    short8 af[4], bf[4];
#pragma unroll
    for (int mi = 0; mi < 4; ++mi)
      af[mi] = *(const short8*)(As + (wm * 64 + mi * 16 + l15) * 128 + es);
#pragma unroll
    for (int ni = 0; ni < 4; ++ni)
      bf[ni] = *(const short8*)(Bs + (wn * 64 + ni * 16 + l15) * 128 + es);
#pragma unroll
    for (int mi = 0; mi < 4; ++mi)
#pragma unroll
      for (int ni = 0; ni < 4; ++ni)
        acc[mi][ni] = __builtin_amdgcn_mfma_f32_16x16x32_bf16(af[mi], bf[ni], acc[mi][ni], 0, 0, 0);
  }
  __syncthreads();                       // staging reads done; reuse LDS
  float* Cs = (float*)smem;              // 64KB f32 [128][128], swizzled cols
#pragma unroll
  for (int mi = 0; mi < 4; ++mi) {
#pragma unroll
    for (int ni = 0; ni < 4; ++ni) {
      const int col = wn * 64 + ni * 16 + l15;
#pragma unroll
      for (int r = 0; r < 4; ++r) {
        const int row = wm * 64 + mi * 16 + l4 * 4 + r;
        Cs[row * 128 + (col ^ xsw(row))] = acc[mi][ni][r];
      }
    }
  }
  __syncthreads();
  const int rof = t >> 5;                // 0..7
  const int c0 = (t & 31) * 4;           // 0..124
#pragma unroll
  for (int i = 0; i < 16; ++i) {
    const int row = i * 8 + rof;
    const int grow = bmi * 128 + row;
    if (grow < NN) {
      f32x4 v = *(const f32x4*)(&Cs[row * 128 + (c0 ^ xsw(row))]);
      const int gcol = bni * 128 + c0;
      if (gcol + 3 < NN) {
        *(f32x4*)(adj + (long)grow * NN + gcol) = v;
      } else {
#pragma unroll
        for (int e2 = 0; e2 < 4; ++e2)
          if (gcol + e2 < NN) adj[(long)grow * NN + gcol + e2] = v[e2];
      }
    }
  }
}

// ---------------- launch ----------------
extern "C" void kernel_launch(void* const* d_in, const int* in_sizes, int n_in,
                              void* d_out, int out_size, void* d_ws, size_t ws_size,
                              hipStream_t stream) {
  (void)in_sizes; (void)n_in; (void)out_size; (void)ws_size;
  const float* feat = (const float*)d_in[0];
  const float* W1   = (const float*)d_in[1];
  const float* b1   = (const float*)d_in[2];
  const float* W2   = (const float*)d_in[3];
  const float* b2   = (const float*)d_in[4];
  const float* ew   = (const float*)d_in[5];
  const int*   srcv = (const int*)d_in[6];
  const int*   dstv = (const int*)d_in[7];

  float* zout = (float*)d_out;
  float* adj  = zout + (long)NN * HH2;

  // workspace layout
  float* ht1  = (float*)d_ws;                 // NN*HH1 f32 = partial 0; later ht2
  float* hbuf = ht1 + (long)NN * HH1;         // NN*HH1 f32 = partial 1; later h
  short* w1b  = (short*)(hbuf + (long)NN * HH1); // NN*HH1 bf16
  short* zb   = w1b + (long)NN * HH1;         // NN*HH2 bf16 (pre-swizzled)
  int*   degi = (int*)(zb + (long)NN * HH2);  // NN
  int*   rowst = degi + NN;                   // NN+1 (pad 16)
  int*   cursor = rowst + NN + 16;            // NN
  int*   csrc = cursor + NN;                  // EE
  float* cw   = (float*)(csrc + EE);          // EE
  float* invd = cw + EE;                      // NN
  float* P2   = invd + NN + 16;               // NN*HH1 f32 = partial 2
  float* P3   = P2 + (long)NN * HH1;          // NN*HH1 f32 = partial 3
  float* ht2  = ht1;                          // alias (ht1 dead after k_agg1)

  hipMemsetAsync(degi, 0, NN * sizeof(int), stream);
  k_count<<<(EE + 255) / 256, 256, 0, stream>>>(dstv, degi);
  k_scan<<<1, 1024, 0, stream>>>(degi, rowst, cursor, invd);
  k_fill<<<(EE + 255) / 256, 256, 0, stream>>>(srcv, dstv, ew, cursor, csrc, cw);
  k_w1bf<<<1250, 256, 0, stream>>>(W1, w1b);
  k_gemm1<<<157 * NSPLIT, 256, 0, stream>>>(feat, w1b, ht1, hbuf, P2, P3);
  k_red1<<<2500, 256, 0, stream>>>(ht1, hbuf, P2, P3, ht1);
  k_agg1<<<NN, 256, 0, stream>>>(ht1, rowst, csrc, cw, invd, b1, hbuf);
  k_gemm2<<<625, 512, 0, stream>>>(hbuf, W2, ht2);
  k_agg2<<<NN, 128, 0, stream>>>(ht2, rowst, csrc, cw, invd, b2, zout, zb);
  k_adj<<<dim3(79, 79), 256, 0, stream>>>(zb, adj);
}

// Round 9
// 515.650 us; speedup vs baseline: 1.2685x; 1.0894x over previous
//
#include <hip/hip_runtime.h>
#include <stdint.h>

#define NN 10000
#define EE 320000
#define HH1 256
#define HH2 128
#define NSPLIT 4
#define KCH 2560   // K chunk per split (last split: 2320 = 36*64 + 16 tail)

typedef __attribute__((ext_vector_type(8))) short short8;
typedef __attribute__((ext_vector_type(4))) float f32x4;

// RNE f32->bf16 via native cast (compiler packs to v_cvt_pk_bf16_f32).
static __device__ __forceinline__ short f2bf(float f) {
  union { __bf16 h; short s; } u;
  u.h = (__bf16)f;
  return u.s;
}

static __device__ __forceinline__ short8 cvt8(f32x4 a, f32x4 b) {
  short8 o;
  o[0] = f2bf(a[0]); o[1] = f2bf(a[1]); o[2] = f2bf(a[2]); o[3] = f2bf(a[3]);
  o[4] = f2bf(b[0]); o[5] = f2bf(b[1]); o[6] = f2bf(b[2]); o[7] = f2bf(b[3]);
  return o;
}

// ---------------- graph prep ----------------
__global__ void k_count(const int* __restrict__ dst, int* __restrict__ degi) {
  int e = blockIdx.x * 256 + threadIdx.x;
  if (e < EE) atomicAdd(&degi[dst[e]], 1);
}

__global__ __launch_bounds__(1024) void k_scan(const int* __restrict__ degi,
    int* __restrict__ rowst, int* __restrict__ cursor, float* __restrict__ invd) {
  __shared__ int part[1024];
  const int t = threadIdx.x;
  const int chunk = (NN + 1023) / 1024;
  int b = t * chunk, e = b + chunk;
  if (e > NN) e = NN;
  int s = 0;
  for (int i = b; i < e; ++i) s += degi[i];
  part[t] = s;
  __syncthreads();
  for (int off = 1; off < 1024; off <<= 1) {
    int v = (t >= off) ? part[t - off] : 0;
    __syncthreads();
    part[t] += v;
    __syncthreads();
  }
  int base = (t == 0) ? 0 : part[t - 1];
  for (int i = b; i < e; ++i) {
    rowst[i] = base;
    cursor[i] = base;
    invd[i] = 1.0f / (float)(degi[i] + 1);
    base += degi[i];
  }
  if (t == 1023) rowst[NN] = part[1023];
}

__global__ void k_fill(const int* __restrict__ src, const int* __restrict__ dst,
    const float* __restrict__ ew, int* __restrict__ cursor,
    int* __restrict__ csrc, float* __restrict__ cw) {
  int e = blockIdx.x * 256 + threadIdx.x;
  if (e < EE) {
    int p = atomicAdd(&cursor[dst[e]], 1);
    csrc[p] = src[e];
    cw[p] = ew[e];
  }
}

// ---------------- W1 -> bf16 ----------------
__global__ void k_w1bf(const float* __restrict__ W1, short* __restrict__ w1b) {
  long i = (long)(blockIdx.x * 256 + threadIdx.x) * 8;
  float4 a = *(const float4*)(W1 + i);
  float4 b = *(const float4*)(W1 + i + 4);
  short8 o;
  o[0] = f2bf(a.x); o[1] = f2bf(a.y); o[2] = f2bf(a.z); o[3] = f2bf(a.w);
  o[4] = f2bf(b.x); o[5] = f2bf(b.y); o[6] = f2bf(b.z); o[7] = f2bf(b.w);
  *(short8*)(w1b + i) = o;
}

// ---------------- GEMM1: ht1 = feat @ W1^T ----------------
// BM=64, BN=256 (feat read once), BK=64, 512 threads = 8 waves (2m x 4n),
// wave-tile 32x64. Double-buffered A+B LDS (80KB), ONE barrier per chunk.
// CORRECTNESS (r8 lesson, rule #18): the A-path cvt8 is register-only VALU,
// so a bare "memory"-clobber vmcnt(0) does NOT order it — hipcc hoisted it
// above the wait and staged pre-load (zero) registers. Fix: the waitcnt asm
// takes ra0/ra1 as "+v" in/outs (data dependency) + sched_barrier(0).
__global__ __launch_bounds__(512, 4) void k_gemm1(const float* __restrict__ feat,
    const short* __restrict__ w1b, float* __restrict__ P0, float* __restrict__ P1,
    float* __restrict__ P2, float* __restrict__ P3) {
  __shared__ short Abuf[2][64 * 64];    // 16KB  bf16, slot^(row&7) swizzle
  __shared__ short Bbuf[2][256 * 64];   // 64KB
  const int bid = (int)blockIdx.x;
  const int sp = bid / 157;
  const int bm = bid - sp * 157;
  const int ks = sp * KCH;
  const int ke = (ks + KCH < NN) ? ks + KCH : NN;
  float* __restrict__ outp = (sp == 0) ? P0 : (sp == 1) ? P1 : (sp == 2) ? P2 : P3;

  const int t = threadIdx.x;            // 0..511
  const int lane = t & 63;
  const int wid = t >> 6;               // 0..7
  const int wm = wid >> 2, wn = wid & 3;
  const int l15 = lane & 15, l4 = lane >> 4;
  const int ar = t >> 3, q = t & 7;     // A staging: row 0..63, col-octant
  const long abase = (long)min(bm * 64 + ar, NN - 1) * NN + q * 8;
  const int br = t >> 1, h = t & 1;     // B staging: row 0..255, half
  const long bbase = (long)br * NN + h * 32;

  f32x4 acc[2][4];
  const f32x4 zz = {0.f, 0.f, 0.f, 0.f};
#pragma unroll
  for (int mi = 0; mi < 2; ++mi)
#pragma unroll
    for (int ni = 0; ni < 4; ++ni) acc[mi][ni] = zz;

  f32x4 ra0, ra1;
  short8 rb0, rb1, rb2, rb3;

#define GLOAD_A(PTR)                                                           \
  asm volatile("global_load_dwordx4 %0, %2, off\n\t"                           \
               "global_load_dwordx4 %1, %2, off offset:16"                     \
               : "=&v"(ra0), "=&v"(ra1) : "v"(PTR) : "memory")

#define GLOAD_B(PTR)                                                           \
  asm volatile("global_load_dwordx4 %0, %4, off\n\t"                           \
               "global_load_dwordx4 %1, %4, off offset:16\n\t"                 \
               "global_load_dwordx4 %2, %4, off offset:32\n\t"                 \
               "global_load_dwordx4 %3, %4, off offset:48"                     \
               : "=&v"(rb0), "=&v"(rb1), "=&v"(rb2), "=&v"(rb3)                \
               : "v"(PTR) : "memory")

// Wait for outstanding loads AND tie the A registers through the asm so any
// consumer (the register-only cvt8) is data-dependent on the wait.
#define VMWAIT_TIED() do {                                                     \
    asm volatile("s_waitcnt vmcnt(0)"                                          \
                 : "+v"(ra0), "+v"(ra1), "+v"(rb0), "+v"(rb1),                 \
                   "+v"(rb2), "+v"(rb3) :: "memory");                          \
    __builtin_amdgcn_sched_barrier(0);                                         \
  } while (0)

#define STAGE(PB) do {                                                         \
    *(short8*)(&Abuf[PB][ar * 64 + ((q ^ (ar & 7)) * 8)]) = cvt8(ra0, ra1);    \
    *(short8*)(&Bbuf[PB][br * 64 + ((((h << 2) | 0) ^ (br & 7)) * 8)]) = rb0;  \
    *(short8*)(&Bbuf[PB][br * 64 + ((((h << 2) | 1) ^ (br & 7)) * 8)]) = rb1;  \
    *(short8*)(&Bbuf[PB][br * 64 + ((((h << 2) | 2) ^ (br & 7)) * 8)]) = rb2;  \
    *(short8*)(&Bbuf[PB][br * 64 + ((((h << 2) | 3) ^ (br & 7)) * 8)]) = rb3;  \
  } while (0)

  const int nch = (ke - ks) >> 6;   // 40,40,40,36
  GLOAD_A(feat + abase + ks);
  GLOAD_B(w1b + bbase + ks);
  VMWAIT_TIED();
  STAGE(0);
  GLOAD_A(feat + abase + ks + 64);
  GLOAD_B(w1b + bbase + ks + 64);
  asm volatile("s_waitcnt lgkmcnt(0)" ::: "memory");
  asm volatile("s_barrier" ::: "memory");

  int p = 0;
  for (int ci = 0; ci < nch; ++ci) {
#pragma unroll
    for (int kk = 0; kk < 2; ++kk) {
      const int es = ((kk * 4 + l4) ^ (l15 & 7)) * 8;
      const short8 af0 = *(const short8*)(&Abuf[p][(wm * 32 + l15) * 64 + es]);
      const short8 af1 = *(const short8*)(&Abuf[p][(wm * 32 + 16 + l15) * 64 + es]);
#pragma unroll
      for (int ni = 0; ni < 4; ++ni) {
        const short8 bf = *(const short8*)(&Bbuf[p][(wn * 64 + ni * 16 + l15) * 64 + es]);
        acc[0][ni] = __builtin_amdgcn_mfma_f32_16x16x32_bf16(af0, bf, acc[0][ni], 0, 0, 0);
        acc[1][ni] = __builtin_amdgcn_mfma_f32_16x16x32_bf16(af1, bf, acc[1][ni], 0, 0, 0);
      }
    }
    if (ci + 1 < nch) {
      VMWAIT_TIED();                                     // chunk ci+1 regs landed
      STAGE(p ^ 1);
      if (ci + 2 < nch) {
        const int kn = ks + (ci + 2) * 64;
        GLOAD_A(feat + abase + kn);
        GLOAD_B(w1b + bbase + kn);
      }
    }
    asm volatile("s_waitcnt lgkmcnt(0)" ::: "memory");   // ds reads+writes done
    asm volatile("s_barrier" ::: "memory");
    p ^= 1;
  }
#undef GLOAD_A
#undef GLOAD_B
#undef VMWAIT_TIED
#undef STAGE

  // K tail (sp==3): 16 columns, reg-direct MFMA; lanes l4>=2 contribute 0.
  if (ks + (nch << 6) < ke) {
    const int kt = ks + (nch << 6);                      // 9984
    const short8 z8 = {0, 0, 0, 0, 0, 0, 0, 0};
    short8 aft0 = z8, aft1 = z8;
    short8 bft[4];
#pragma unroll
    for (int ni = 0; ni < 4; ++ni) bft[ni] = z8;
    if (l4 < 2) {
      const long Ra0 = (long)min(bm * 64 + wm * 32 + l15, NN - 1) * NN + kt + l4 * 8;
      const long Ra1 = (long)min(bm * 64 + wm * 32 + 16 + l15, NN - 1) * NN + kt + l4 * 8;
      f32x4 lo0 = *(const f32x4*)(feat + Ra0);
      f32x4 hi0 = *(const f32x4*)(feat + Ra0 + 4);
      f32x4 lo1 = *(const f32x4*)(feat + Ra1);
      f32x4 hi1 = *(const f32x4*)(feat + Ra1 + 4);
      aft0 = cvt8(lo0, hi0);
      aft1 = cvt8(lo1, hi1);
#pragma unroll
      for (int ni = 0; ni < 4; ++ni)
        bft[ni] = *(const short8*)(w1b + (long)(wn * 64 + ni * 16 + l15) * NN + kt + l4 * 8);
    }
#pragma unroll
    for (int ni = 0; ni < 4; ++ni) {
      acc[0][ni] = __builtin_amdgcn_mfma_f32_16x16x32_bf16(aft0, bft[ni], acc[0][ni], 0, 0, 0);
      acc[1][ni] = __builtin_amdgcn_mfma_f32_16x16x32_bf16(aft1, bft[ni], acc[1][ni], 0, 0, 0);
    }
  }

  // epilogue: write 64x256 f32 partial
#pragma unroll
  for (int mi = 0; mi < 2; ++mi) {
#pragma unroll
    for (int ni = 0; ni < 4; ++ni) {
      const int col = wn * 64 + ni * 16 + l15;
      const int r0 = bm * 64 + wm * 32 + mi * 16 + l4 * 4;
#pragma unroll
      for (int r2 = 0; r2 < 4; ++r2) {
        const int row = r0 + r2;
        if (row < NN) outp[(long)row * HH1 + col] = acc[mi][ni][r2];
      }
    }
  }
}

// ---------------- reduce 4 partials -> ht1 --------------
__global__ void k_red1(const float* __restrict__ P0, const float* __restrict__ P1,
    const float* __restrict__ P2, const float* __restrict__ P3,
    float* __restrict__ o) {
  const long i = (long)(blockIdx.x * 256 + threadIdx.x) * 4;
  f32x4 a = *(const f32x4*)(P0 + i);
  f32x4 b = *(const f32x4*)(P1 + i);
  f32x4 c = *(const f32x4*)(P2 + i);
  f32x4 d = *(const f32x4*)(P3 + i);
  *(f32x4*)(o + i) = (a + b) + (c + d);
}

// ---------------- aggregate layer 1 (+relu) ----------------
__global__ void k_agg1(const float* __restrict__ ht1, const int* __restrict__ rowst,
    const int* __restrict__ csrc, const float* __restrict__ cw,
    const float* __restrict__ invd, const float* __restrict__ b1,
    float* __restrict__ h) {
  const int node = blockIdx.x;
  const int j = threadIdx.x;
  const int s = rowst[node], e = rowst[node + 1];
  float acc = 0.f;
  for (int p = s; p < e; ++p)
    acc = fmaf(cw[p], ht1[(long)csrc[p] * HH1 + j], acc);
  float v = (acc + ht1[(long)node * HH1 + j]) * invd[node] + b1[j];
  h[(long)node * HH1 + j] = fmaxf(v, 0.f);
}

// ---------------- GEMM2: ht2 = h @ W2^T (f32 VALU) ----------------
__global__ __launch_bounds__(512) void k_gemm2(const float* __restrict__ h,
    const float* __restrict__ W2, float* __restrict__ ht2) {
  const int t = threadIdx.x;
  const int col = t & 127, rg = t >> 7;  // rg 0..3
  const long row0 = (long)blockIdx.x * 16 + rg * 4;
  const float* hp = h + row0 * HH1;
  const float* wp = W2 + col * HH1;
  float acc0 = 0.f, acc1 = 0.f, acc2 = 0.f, acc3 = 0.f;
  for (int k = 0; k < HH1; k += 4) {
    float4 wv = *(const float4*)(wp + k);
    float4 h0 = *(const float4*)(hp + k);
    float4 h1 = *(const float4*)(hp + HH1 + k);
    float4 h2 = *(const float4*)(hp + 2 * HH1 + k);
    float4 h3 = *(const float4*)(hp + 3 * HH1 + k);
    acc0 += h0.x * wv.x + h0.y * wv.y + h0.z * wv.z + h0.w * wv.w;
    acc1 += h1.x * wv.x + h1.y * wv.y + h1.z * wv.z + h1.w * wv.w;
    acc2 += h2.x * wv.x + h2.y * wv.y + h2.z * wv.z + h2.w * wv.w;
    acc3 += h3.x * wv.x + h3.y * wv.y + h3.z * wv.z + h3.w * wv.w;
  }
  ht2[row0 * HH2 + col] = acc0;
  ht2[(row0 + 1) * HH2 + col] = acc1;
  ht2[(row0 + 2) * HH2 + col] = acc2;
  ht2[(row0 + 3) * HH2 + col] = acc3;
}

// ---------------- aggregate layer 2 -> z (f32 out) + pre-swizzled bf16 ------
__global__ void k_agg2(const float* __restrict__ ht2, const int* __restrict__ rowst,
    const int* __restrict__ csrc, const float* __restrict__ cw,
    const float* __restrict__ invd, const float* __restrict__ b2,
    float* __restrict__ zout, short* __restrict__ zb) {
  const int node = blockIdx.x;
  const int j = threadIdx.x;
  const int s = rowst[node], e = rowst[node + 1];
  float acc = 0.f;
  for (int p = s; p < e; ++p)
    acc = fmaf(cw[p], ht2[(long)csrc[p] * HH2 + j], acc);
  float v = (acc + ht2[(long)node * HH2 + j]) * invd[node] + b2[j];
  zout[(long)node * HH2 + j] = v;
  const int slot = j >> 3, pos = j & 7;
  zb[node * HH2 + ((slot ^ (node & 15)) << 3) + pos] = f2bf(v);
}

// ---------------- adj = z @ z^T (bf16 MFMA, K=128, tile 128x128) ------------
// Epilogue: LDS-transpose accumulators then nontemporal dwordx4 stores
// (adj is write-once, never re-read -> skip L2 allocation).
static __device__ __forceinline__ int xsw(int row) {
  return (((row >> 2) & 1) << 4) ^ (((row >> 3) & 3) << 2);
}

__global__ __launch_bounds__(256) void k_adj(const short* __restrict__ zb,
                                             float* __restrict__ adj) {
  __shared__ __align__(16) char smem[65536];
  short* As = (short*)smem;            // 32KB bf16 [128][128]
  short* Bs = (short*)(smem + 32768);  // 32KB
  const int bmi = blockIdx.y, bni = blockIdx.x;
  const int t = threadIdx.x;
  const int lane = t & 63;
  const int wid = t >> 6;
  const int wm = wid >> 1, wn = wid & 1;
  const int l15 = lane & 15, l4 = lane >> 4;
  const int sr = t >> 4;   // 0..15
  const int ss = t & 15;
#pragma unroll
  for (int it = 0; it < 8; ++it) {
    const int r = it * 16 + sr;
    const long ga = (long)min(bmi * 128 + r, NN - 1) * HH2;
    const long gb = (long)min(bni * 128 + r, NN - 1) * HH2;
    *(short8*)(As + r * 128 + ss * 8) = *(const short8*)(zb + ga + ss * 8);
    *(short8*)(Bs + r * 128 + ss * 8) = *(const short8*)(zb + gb + ss * 8);
  }
  __syncthreads();
  f32x4 acc[4][4];
  const f32x4 zz = {0.f, 0.f, 0.f, 0.f};
#pragma unroll
  for (int mi = 0; mi < 4; ++mi)
#pragma unroll
    for (int ni = 0; ni < 4; ++ni) acc[mi][ni] = zz;
#pragma unroll
  for (int k4 = 0; k4 < 4; ++k4) {
    const int es = ((k4 * 4 + l4) ^ l15) * 8;
    short8 af[4], bf[4];
#pragma unroll
    for (int mi = 0; mi < 4; ++mi)
      af[mi] = *(const short8*)(As + (wm * 64 + mi * 16 + l15) * 128 + es);
#pragma unroll
    for (int ni = 0; ni < 4; ++ni)
      bf[ni] = *(const short8*)(Bs + (wn * 64 + ni * 16 + l15) * 128 + es);
#pragma unroll
    for (int mi = 0; mi < 4; ++mi)
#pragma unroll
      for (int ni = 0; ni < 4; ++ni)
        acc[mi][ni] = __builtin_amdgcn_mfma_f32_16x16x32_bf16(af[mi], bf[ni], acc[mi][ni], 0, 0, 0);
  }
  __syncthreads();                       // staging reads done; reuse LDS
  float* Cs = (float*)smem;              // 64KB f32 [128][128], swizzled cols
#pragma unroll
  for (int mi = 0; mi < 4; ++mi) {
#pragma unroll
    for (int ni = 0; ni < 4; ++ni) {
      const int col = wn * 64 + ni * 16 + l15;
#pragma unroll
      for (int r = 0; r < 4; ++r) {
        const int row = wm * 64 + mi * 16 + l4 * 4 + r;
        Cs[row * 128 + (col ^ xsw(row))] = acc[mi][ni][r];
      }
    }
  }
  __syncthreads();
  const int rof = t >> 5;                // 0..7
  const int c0 = (t & 31) * 4;           // 0..124
#pragma unroll
  for (int i = 0; i < 16; ++i) {
    const int row = i * 8 + rof;
    const int grow = bmi * 128 + row;
    if (grow < NN) {
      f32x4 v = *(const f32x4*)(&Cs[row * 128 + (c0 ^ xsw(row))]);
      const int gcol = bni * 128 + c0;
      if (gcol + 3 < NN) {
        __builtin_nontemporal_store(v, (f32x4*)(adj + (long)grow * NN + gcol));
      } else {
#pragma unroll
        for (int e2 = 0; e2 < 4; ++e2)
          if (gcol + e2 < NN) adj[(long)grow * NN + gcol + e2] = v[e2];
      }
    }
  }
}

// ---------------- launch ----------------
extern "C" void kernel_launch(void* const* d_in, const int* in_sizes, int n_in,
                              void* d_out, int out_size, void* d_ws, size_t ws_size,
                              hipStream_t stream) {
  (void)in_sizes; (void)n_in; (void)out_size; (void)ws_size;
  const float* feat = (const float*)d_in[0];
  const float* W1   = (const float*)d_in[1];
  const float* b1   = (const float*)d_in[2];
  const float* W2   = (const float*)d_in[3];
  const float* b2   = (const float*)d_in[4];
  const float* ew   = (const float*)d_in[5];
  const int*   srcv = (const int*)d_in[6];
  const int*   dstv = (const int*)d_in[7];

  float* zout = (float*)d_out;
  float* adj  = zout + (long)NN * HH2;

  // workspace layout
  float* ht1  = (float*)d_ws;                 // NN*HH1 f32 = partial 0; later ht2
  float* hbuf = ht1 + (long)NN * HH1;         // NN*HH1 f32 = partial 1; later h
  short* w1b  = (short*)(hbuf + (long)NN * HH1); // NN*HH1 bf16
  short* zb   = w1b + (long)NN * HH1;         // NN*HH2 bf16 (pre-swizzled)
  int*   degi = (int*)(zb + (long)NN * HH2);  // NN
  int*   rowst = degi + NN;                   // NN+1 (pad 16)
  int*   cursor = rowst + NN + 16;            // NN
  int*   csrc = cursor + NN;                  // EE
  float* cw   = (float*)(csrc + EE);          // EE
  float* invd = cw + EE;                      // NN
  float* P2   = invd + NN + 16;               // NN*HH1 f32 = partial 2
  float* P3   = P2 + (long)NN * HH1;          // NN*HH1 f32 = partial 3
  float* ht2  = ht1;                          // alias (ht1 dead after k_agg1)

  hipMemsetAsync(degi, 0, NN * sizeof(int), stream);
  k_count<<<(EE + 255) / 256, 256, 0, stream>>>(dstv, degi);
  k_scan<<<1, 1024, 0, stream>>>(degi, rowst, cursor, invd);
  k_fill<<<(EE + 255) / 256, 256, 0, stream>>>(srcv, dstv, ew, cursor, csrc, cw);
  k_w1bf<<<1250, 256, 0, stream>>>(W1, w1b);
  k_gemm1<<<157 * NSPLIT, 512, 0, stream>>>(feat, w1b, ht1, hbuf, P2, P3);
  k_red1<<<2500, 256, 0, stream>>>(ht1, hbuf, P2, P3, ht1);
  k_agg1<<<NN, 256, 0, stream>>>(ht1, rowst, csrc, cw, invd, b1, hbuf);
  k_gemm2<<<625, 512, 0, stream>>>(hbuf, W2, ht2);
  k_agg2<<<NN, 128, 0, stream>>>(ht2, rowst, csrc, cw, invd, b2, zout, zb);
  k_adj<<<dim3(79, 79), 256, 0, stream>>>(zb, adj);
}

// Round 10
// 495.402 us; speedup vs baseline: 1.3203x; 1.0409x over previous
//
#include <hip/hip_runtime.h>
#include <stdint.h>

#define NN 10000
#define EE 320000
#define HH1 256
#define HH2 128
#define NSPLIT 4
#define KCH 2560   // K chunk per split (last split: 2320 = 36*64 + 16 tail)

typedef __attribute__((ext_vector_type(8))) short short8;
typedef __attribute__((ext_vector_type(4))) float f32x4;

// RNE f32->bf16 via native cast (compiler packs to v_cvt_pk_bf16_f32).
static __device__ __forceinline__ short f2bf(float f) {
  union { __bf16 h; short s; } u;
  u.h = (__bf16)f;
  return u.s;
}

static __device__ __forceinline__ short8 cvt8(f32x4 a, f32x4 b) {
  short8 o;
  o[0] = f2bf(a[0]); o[1] = f2bf(a[1]); o[2] = f2bf(a[2]); o[3] = f2bf(a[3]);
  o[4] = f2bf(b[0]); o[5] = f2bf(b[1]); o[6] = f2bf(b[2]); o[7] = f2bf(b[3]);
  return o;
}

// ---------------- graph prep ----------------
__global__ void k_count(const int* __restrict__ dst, int* __restrict__ degi) {
  int e = blockIdx.x * 256 + threadIdx.x;
  if (e < EE) atomicAdd(&degi[dst[e]], 1);
}

__global__ __launch_bounds__(1024) void k_scan(const int* __restrict__ degi,
    int* __restrict__ rowst, int* __restrict__ cursor, float* __restrict__ invd) {
  __shared__ int part[1024];
  const int t = threadIdx.x;
  const int chunk = (NN + 1023) / 1024;
  int b = t * chunk, e = b + chunk;
  if (e > NN) e = NN;
  int s = 0;
  for (int i = b; i < e; ++i) s += degi[i];
  part[t] = s;
  __syncthreads();
  for (int off = 1; off < 1024; off <<= 1) {
    int v = (t >= off) ? part[t - off] : 0;
    __syncthreads();
    part[t] += v;
    __syncthreads();
  }
  int base = (t == 0) ? 0 : part[t - 1];
  for (int i = b; i < e; ++i) {
    rowst[i] = base;
    cursor[i] = base;
    invd[i] = 1.0f / (float)(degi[i] + 1);
    base += degi[i];
  }
  if (t == 1023) rowst[NN] = part[1023];
}

__global__ void k_fill(const int* __restrict__ src, const int* __restrict__ dst,
    const float* __restrict__ ew, int* __restrict__ cursor,
    int* __restrict__ csrc, float* __restrict__ cw) {
  int e = blockIdx.x * 256 + threadIdx.x;
  if (e < EE) {
    int p = atomicAdd(&cursor[dst[e]], 1);
    csrc[p] = src[e];
    cw[p] = ew[e];
  }
}

// ---------------- W1 -> bf16 ----------------
__global__ void k_w1bf(const float* __restrict__ W1, short* __restrict__ w1b) {
  long i = (long)(blockIdx.x * 256 + threadIdx.x) * 8;
  float4 a = *(const float4*)(W1 + i);
  float4 b = *(const float4*)(W1 + i + 4);
  short8 o;
  o[0] = f2bf(a.x); o[1] = f2bf(a.y); o[2] = f2bf(a.z); o[3] = f2bf(a.w);
  o[4] = f2bf(b.x); o[5] = f2bf(b.y); o[6] = f2bf(b.z); o[7] = f2bf(b.w);
  *(short8*)(w1b + i) = o;
}

// ---------------- GEMM1: ht1 = feat @ W1^T ----------------
// BM=64, BN=256 (feat read once), BK=64, 512 threads = 8 waves (2m x 4n).
// B staged via global_load_lds (linear dest + inverse-swizzled SOURCE, m173/
// rule #21: the XOR slot swizzle is an involution). A reg-staged (needs cvt),
// r8/r9 lesson: vmcnt wait is TIED to the A regs so the register-only cvt8
// cannot be hoisted above it. One barrier per chunk; B-DMA(ci+1)->p^1 issued
// at top of chunk ci (p^1 readers sealed at the ci-1 barrier).
__global__ __launch_bounds__(512, 4) void k_gemm1(const float* __restrict__ feat,
    const short* __restrict__ w1b, float* __restrict__ P0, float* __restrict__ P1,
    float* __restrict__ P2, float* __restrict__ P3) {
  __shared__ short Abuf[2][64 * 64];    // 16KB  bf16, slot^(row&7) swizzle
  __shared__ short Bbuf[2][256 * 64];   // 64KB  bf16, same swizzle (via source)
  const int bid = (int)blockIdx.x;
  const int sp = bid / 157;
  const int bm = bid - sp * 157;
  const int ks = sp * KCH;
  const int ke = (ks + KCH < NN) ? ks + KCH : NN;
  float* __restrict__ outp = (sp == 0) ? P0 : (sp == 1) ? P1 : (sp == 2) ? P2 : P3;

  const int t = threadIdx.x;            // 0..511
  const int lane = t & 63;
  const int wid = t >> 6;               // 0..7
  const int wm = wid >> 2, wn = wid & 3;
  const int l15 = lane & 15, l4 = lane >> 4;
  const int ar = t >> 3, q = t & 7;     // A staging: row 0..63, col-octant
  const long abase = (long)min(bm * 64 + ar, NN - 1) * NN + q * 8;
  // B DMA: issue j covers LDS granules g = j*512 + t (16B each):
  //   row r = g>>3 = j*64 + (t>>3), linear slot s_lds = t&7.
  //   source granule = s_lds ^ (r&7)  (involution of the read-side swizzle).
  const int bswz = ((t & 7) ^ ((t >> 3) & 7)) << 3;   // elements
  const long bsrc0 = (long)(0 * 64 + (t >> 3)) * NN + bswz;
  const long bsrc1 = (long)(1 * 64 + (t >> 3)) * NN + bswz;
  const long bsrc2 = (long)(2 * 64 + (t >> 3)) * NN + bswz;
  const long bsrc3 = (long)(3 * 64 + (t >> 3)) * NN + bswz;

  f32x4 acc[2][4];
  const f32x4 zz = {0.f, 0.f, 0.f, 0.f};
#pragma unroll
  for (int mi = 0; mi < 2; ++mi)
#pragma unroll
    for (int ni = 0; ni < 4; ++ni) acc[mi][ni] = zz;

  f32x4 ra0, ra1;

#define GLOAD_A(PTR)                                                           \
  asm volatile("global_load_dwordx4 %0, %2, off\n\t"                           \
               "global_load_dwordx4 %1, %2, off offset:16"                     \
               : "=&v"(ra0), "=&v"(ra1) : "v"(PTR) : "memory")

#define ISSUE_B(K0, PB) do {                                                   \
    char* _d = (char*)&Bbuf[PB][0] + t * 16;                                   \
    __builtin_amdgcn_global_load_lds(                                          \
        (const __attribute__((address_space(1))) unsigned int*)(w1b + bsrc0 + (K0)), \
        (__attribute__((address_space(3))) unsigned int*)(_d), 16, 0, 0);      \
    __builtin_amdgcn_global_load_lds(                                          \
        (const __attribute__((address_space(1))) unsigned int*)(w1b + bsrc1 + (K0)), \
        (__attribute__((address_space(3))) unsigned int*)(_d + 8192), 16, 0, 0); \
    __builtin_amdgcn_global_load_lds(                                          \
        (const __attribute__((address_space(1))) unsigned int*)(w1b + bsrc2 + (K0)), \
        (__attribute__((address_space(3))) unsigned int*)(_d + 16384), 16, 0, 0); \
    __builtin_amdgcn_global_load_lds(                                          \
        (const __attribute__((address_space(1))) unsigned int*)(w1b + bsrc3 + (K0)), \
        (__attribute__((address_space(3))) unsigned int*)(_d + 24576), 16, 0, 0); \
  } while (0)

// Wait for outstanding VMEM (A reg-loads + my B lds-DMA) AND tie the A regs
// through the asm so the register-only cvt8 is data-dependent on the wait.
#define VMWAIT_TIED() do {                                                     \
    asm volatile("s_waitcnt vmcnt(0)" : "+v"(ra0), "+v"(ra1) :: "memory");     \
    __builtin_amdgcn_sched_barrier(0);                                         \
  } while (0)

#define STAGE_A(PB)                                                            \
    *(short8*)(&Abuf[PB][ar * 64 + ((q ^ (ar & 7)) * 8)]) = cvt8(ra0, ra1)

  const int nch = (ke - ks) >> 6;   // 40,40,40,36
  // prologue: chunk 0 staged, chunk 1 A-loads in flight
  ISSUE_B(ks, 0);
  GLOAD_A(feat + abase + ks);
  VMWAIT_TIED();
  STAGE_A(0);
  GLOAD_A(feat + abase + ks + 64);
  asm volatile("s_waitcnt lgkmcnt(0)" ::: "memory");
  asm volatile("s_barrier" ::: "memory");

  int p = 0;
  for (int ci = 0; ci < nch; ++ci) {
    if (ci + 1 < nch) ISSUE_B(ks + (ci + 1) * 64, p ^ 1);
#pragma unroll
    for (int kk = 0; kk < 2; ++kk) {
      const int es = ((kk * 4 + l4) ^ (l15 & 7)) * 8;
      const short8 af0 = *(const short8*)(&Abuf[p][(wm * 32 + l15) * 64 + es]);
      const short8 af1 = *(const short8*)(&Abuf[p][(wm * 32 + 16 + l15) * 64 + es]);
#pragma unroll
      for (int ni = 0; ni < 4; ++ni) {
        const short8 bf = *(const short8*)(&Bbuf[p][(wn * 64 + ni * 16 + l15) * 64 + es]);
        acc[0][ni] = __builtin_amdgcn_mfma_f32_16x16x32_bf16(af0, bf, acc[0][ni], 0, 0, 0);
        acc[1][ni] = __builtin_amdgcn_mfma_f32_16x16x32_bf16(af1, bf, acc[1][ni], 0, 0, 0);
      }
    }
    if (ci + 1 < nch) {
      VMWAIT_TIED();                  // A(ci+1) regs + my B(ci+1) DMA landed
      STAGE_A(p ^ 1);
      if (ci + 2 < nch) GLOAD_A(feat + abase + ks + (ci + 2) * 64);
    }
    asm volatile("s_waitcnt lgkmcnt(0)" ::: "memory");   // my ds reads+writes done
    asm volatile("s_barrier" ::: "memory");
    p ^= 1;
  }
#undef GLOAD_A
#undef ISSUE_B
#undef VMWAIT_TIED
#undef STAGE_A

  // K tail (sp==3): 16 columns, reg-direct MFMA; lanes l4>=2 contribute 0.
  if (ks + (nch << 6) < ke) {
    const int kt = ks + (nch << 6);                      // 9984
    const short8 z8 = {0, 0, 0, 0, 0, 0, 0, 0};
    short8 aft0 = z8, aft1 = z8;
    short8 bft[4];
#pragma unroll
    for (int ni = 0; ni < 4; ++ni) bft[ni] = z8;
    if (l4 < 2) {
      const long Ra0 = (long)min(bm * 64 + wm * 32 + l15, NN - 1) * NN + kt + l4 * 8;
      const long Ra1 = (long)min(bm * 64 + wm * 32 + 16 + l15, NN - 1) * NN + kt + l4 * 8;
      f32x4 lo0 = *(const f32x4*)(feat + Ra0);
      f32x4 hi0 = *(const f32x4*)(feat + Ra0 + 4);
      f32x4 lo1 = *(const f32x4*)(feat + Ra1);
      f32x4 hi1 = *(const f32x4*)(feat + Ra1 + 4);
      aft0 = cvt8(lo0, hi0);
      aft1 = cvt8(lo1, hi1);
#pragma unroll
      for (int ni = 0; ni < 4; ++ni)
        bft[ni] = *(const short8*)(w1b + (long)(wn * 64 + ni * 16 + l15) * NN + kt + l4 * 8);
    }
#pragma unroll
    for (int ni = 0; ni < 4; ++ni) {
      acc[0][ni] = __builtin_amdgcn_mfma_f32_16x16x32_bf16(aft0, bft[ni], acc[0][ni], 0, 0, 0);
      acc[1][ni] = __builtin_amdgcn_mfma_f32_16x16x32_bf16(aft1, bft[ni], acc[1][ni], 0, 0, 0);
    }
  }

  // epilogue: write 64x256 f32 partial
#pragma unroll
  for (int mi = 0; mi < 2; ++mi) {
#pragma unroll
    for (int ni = 0; ni < 4; ++ni) {
      const int col = wn * 64 + ni * 16 + l15;
      const int r0 = bm * 64 + wm * 32 + mi * 16 + l4 * 4;
#pragma unroll
      for (int r2 = 0; r2 < 4; ++r2) {
        const int row = r0 + r2;
        if (row < NN) outp[(long)row * HH1 + col] = acc[mi][ni][r2];
      }
    }
  }
}

// ---------------- reduce 4 partials -> ht1 --------------
__global__ void k_red1(const float* __restrict__ P0, const float* __restrict__ P1,
    const float* __restrict__ P2, const float* __restrict__ P3,
    float* __restrict__ o) {
  const long i = (long)(blockIdx.x * 256 + threadIdx.x) * 4;
  f32x4 a = *(const f32x4*)(P0 + i);
  f32x4 b = *(const f32x4*)(P1 + i);
  f32x4 c = *(const f32x4*)(P2 + i);
  f32x4 d = *(const f32x4*)(P3 + i);
  *(f32x4*)(o + i) = (a + b) + (c + d);
}

// ---------------- aggregate layer 1 (+relu) ----------------
__global__ void k_agg1(const float* __restrict__ ht1, const int* __restrict__ rowst,
    const int* __restrict__ csrc, const float* __restrict__ cw,
    const float* __restrict__ invd, const float* __restrict__ b1,
    float* __restrict__ h) {
  const int node = blockIdx.x;
  const int j = threadIdx.x;
  const int s = rowst[node], e = rowst[node + 1];
  float acc = 0.f;
  for (int p = s; p < e; ++p)
    acc = fmaf(cw[p], ht1[(long)csrc[p] * HH1 + j], acc);
  float v = (acc + ht1[(long)node * HH1 + j]) * invd[node] + b1[j];
  h[(long)node * HH1 + j] = fmaxf(v, 0.f);
}

// ---------------- GEMM2: ht2 = h @ W2^T (f32 VALU) ----------------
__global__ __launch_bounds__(512) void k_gemm2(const float* __restrict__ h,
    const float* __restrict__ W2, float* __restrict__ ht2) {
  const int t = threadIdx.x;
  const int col = t & 127, rg = t >> 7;  // rg 0..3
  const long row0 = (long)blockIdx.x * 16 + rg * 4;
  const float* hp = h + row0 * HH1;
  const float* wp = W2 + col * HH1;
  float acc0 = 0.f, acc1 = 0.f, acc2 = 0.f, acc3 = 0.f;
  for (int k = 0; k < HH1; k += 4) {
    float4 wv = *(const float4*)(wp + k);
    float4 h0 = *(const float4*)(hp + k);
    float4 h1 = *(const float4*)(hp + HH1 + k);
    float4 h2 = *(const float4*)(hp + 2 * HH1 + k);
    float4 h3 = *(const float4*)(hp + 3 * HH1 + k);
    acc0 += h0.x * wv.x + h0.y * wv.y + h0.z * wv.z + h0.w * wv.w;
    acc1 += h1.x * wv.x + h1.y * wv.y + h1.z * wv.z + h1.w * wv.w;
    acc2 += h2.x * wv.x + h2.y * wv.y + h2.z * wv.z + h2.w * wv.w;
    acc3 += h3.x * wv.x + h3.y * wv.y + h3.z * wv.z + h3.w * wv.w;
  }
  ht2[row0 * HH2 + col] = acc0;
  ht2[(row0 + 1) * HH2 + col] = acc1;
  ht2[(row0 + 2) * HH2 + col] = acc2;
  ht2[(row0 + 3) * HH2 + col] = acc3;
}

// ---------------- aggregate layer 2 -> z (f32 out) + pre-swizzled bf16 ------
__global__ void k_agg2(const float* __restrict__ ht2, const int* __restrict__ rowst,
    const int* __restrict__ csrc, const float* __restrict__ cw,
    const float* __restrict__ invd, const float* __restrict__ b2,
    float* __restrict__ zout, short* __restrict__ zb) {
  const int node = blockIdx.x;
  const int j = threadIdx.x;
  const int s = rowst[node], e = rowst[node + 1];
  float acc = 0.f;
  for (int p = s; p < e; ++p)
    acc = fmaf(cw[p], ht2[(long)csrc[p] * HH2 + j], acc);
  float v = (acc + ht2[(long)node * HH2 + j]) * invd[node] + b2[j];
  zout[(long)node * HH2 + j] = v;
  const int slot = j >> 3, pos = j & 7;
  zb[node * HH2 + ((slot ^ (node & 15)) << 3) + pos] = f2bf(v);
}

// ---------------- adj = z @ z^T (bf16 MFMA, K=128, tile 128x128) ------------
// Epilogue: LDS-transpose accumulators then nontemporal dwordx4 stores
// (adj is write-once, never re-read -> skip L2 allocation).
static __device__ __forceinline__ int xsw(int row) {
  return (((row >> 2) & 1) << 4) ^ (((row >> 3) & 3) << 2);
}

__global__ __launch_bounds__(256) void k_adj(const short* __restrict__ zb,
                                             float* __restrict__ adj) {
  __shared__ __align__(16) char smem[65536];
  short* As = (short*)smem;            // 32KB bf16 [128][128]
  short* Bs = (short*)(smem + 32768);  // 32KB
  const int bmi = blockIdx.y, bni = blockIdx.x;
  const int t = threadIdx.x;
  const int lane = t & 63;
  const int wid = t >> 6;
  const int wm = wid >> 1, wn = wid & 1;
  const int l15 = lane & 15, l4 = lane >> 4;
  const int sr = t >> 4;   // 0..15
  const int ss = t & 15;
#pragma unroll
  for (int it = 0; it < 8; ++it) {
    const int r = it * 16 + sr;
    const long ga = (long)min(bmi * 128 + r, NN - 1) * HH2;
    const long gb = (long)min(bni * 128 + r, NN - 1) * HH2;
    *(short8*)(As + r * 128 + ss * 8) = *(const short8*)(zb + ga + ss * 8);
    *(short8*)(Bs + r * 128 + ss * 8) = *(const short8*)(zb + gb + ss * 8);
  }
  __syncthreads();
  f32x4 acc[4][4];
  const f32x4 zz = {0.f, 0.f, 0.f, 0.f};
#pragma unroll
  for (int mi = 0; mi < 4; ++mi)
#pragma unroll
    for (int ni = 0; ni < 4; ++ni) acc[mi][ni] = zz;
#pragma unroll
  for (int k4 = 0; k4 < 4; ++k4) {
    const int es = ((k4 * 4 + l4) ^ l15) * 8;
    short8 af[4], bf[4];
#pragma unroll
    for (int mi = 0; mi < 4; ++mi)
      af[mi] = *(const short8*)(As + (wm * 64 + mi * 16 + l15) * 128 + es);
#pragma unroll
    for (int ni = 0; ni < 4; ++ni)
      bf[ni] = *(const short8*)(Bs + (wn * 64 + ni * 16 + l15) * 128 + es);
#pragma unroll
    for (int mi = 0; mi < 4; ++mi)
#pragma unroll
      for (int ni = 0; ni < 4; ++ni)
        acc[mi][ni] = __builtin_amdgcn_mfma_f32_16x16x32_bf16(af[mi], bf[ni], acc[mi][ni], 0, 0, 0);
  }
  __syncthreads();                       // staging reads done; reuse LDS
  float* Cs = (float*)smem;              // 64KB f32 [128][128], swizzled cols
#pragma unroll
  for (int mi = 0; mi < 4; ++mi) {
#pragma unroll
    for (int ni = 0; ni < 4; ++ni) {
      const int col = wn * 64 + ni * 16 + l15;
#pragma unroll
      for (int r = 0; r < 4; ++r) {
        const int row = wm * 64 + mi * 16 + l4 * 4 + r;
        Cs[row * 128 + (col ^ xsw(row))] = acc[mi][ni][r];
      }
    }
  }
  __syncthreads();
  const int rof = t >> 5;                // 0..7
  const int c0 = (t & 31) * 4;           // 0..124
#pragma unroll
  for (int i = 0; i < 16; ++i) {
    const int row = i * 8 + rof;
    const int grow = bmi * 128 + row;
    if (grow < NN) {
      f32x4 v = *(const f32x4*)(&Cs[row * 128 + (c0 ^ xsw(row))]);
      const int gcol = bni * 128 + c0;
      if (gcol + 3 < NN) {
        __builtin_nontemporal_store(v, (f32x4*)(adj + (long)grow * NN + gcol));
      } else {
#pragma unroll
        for (int e2 = 0; e2 < 4; ++e2)
          if (gcol + e2 < NN) adj[(long)grow * NN + gcol + e2] = v[e2];
      }
    }
  }
}

// ---------------- launch ----------------
extern "C" void kernel_launch(void* const* d_in, const int* in_sizes, int n_in,
                              void* d_out, int out_size, void* d_ws, size_t ws_size,
                              hipStream_t stream) {
  (void)in_sizes; (void)n_in; (void)out_size; (void)ws_size;
  const float* feat = (const float*)d_in[0];
  const float* W1   = (const float*)d_in[1];
  const float* b1   = (const float*)d_in[2];
  const float* W2   = (const float*)d_in[3];
  const float* b2   = (const float*)d_in[4];
  const float* ew   = (const float*)d_in[5];
  const int*   srcv = (const int*)d_in[6];
  const int*   dstv = (const int*)d_in[7];

  float* zout = (float*)d_out;
  float* adj  = zout + (long)NN * HH2;

  // workspace layout
  float* ht1  = (float*)d_ws;                 // NN*HH1 f32 = partial 0; later ht2
  float* hbuf = ht1 + (long)NN * HH1;         // NN*HH1 f32 = partial 1; later h
  short* w1b  = (short*)(hbuf + (long)NN * HH1); // NN*HH1 bf16
  short* zb   = w1b + (long)NN * HH1;         // NN*HH2 bf16 (pre-swizzled)
  int*   degi = (int*)(zb + (long)NN * HH2);  // NN
  int*   rowst = degi + NN;                   // NN+1 (pad 16)
  int*   cursor = rowst + NN + 16;            // NN
  int*   csrc = cursor + NN;                  // EE
  float* cw   = (float*)(csrc + EE);          // EE
  float* invd = cw + EE;                      // NN
  float* P2   = invd + NN + 16;               // NN*HH1 f32 = partial 2
  float* P3   = P2 + (long)NN * HH1;          // NN*HH1 f32 = partial 3
  float* ht2  = ht1;                          // alias (ht1 dead after k_agg1)

  hipMemsetAsync(degi, 0, NN * sizeof(int), stream);
  k_count<<<(EE + 255) / 256, 256, 0, stream>>>(dstv, degi);
  k_scan<<<1, 1024, 0, stream>>>(degi, rowst, cursor, invd);
  k_fill<<<(EE + 255) / 256, 256, 0, stream>>>(srcv, dstv, ew, cursor, csrc, cw);
  k_w1bf<<<1250, 256, 0, stream>>>(W1, w1b);
  k_gemm1<<<157 * NSPLIT, 512, 0, stream>>>(feat, w1b, ht1, hbuf, P2, P3);
  k_red1<<<2500, 256, 0, stream>>>(ht1, hbuf, P2, P3, ht1);
  k_agg1<<<NN, 256, 0, stream>>>(ht1, rowst, csrc, cw, invd, b1, hbuf);
  k_gemm2<<<625, 512, 0, stream>>>(hbuf, W2, ht2);
  k_agg2<<<NN, 128, 0, stream>>>(ht2, rowst, csrc, cw, invd, b2, zout, zb);
  k_adj<<<dim3(79, 79), 256, 0, stream>>>(zb, adj);
}